// Round 11
// baseline (104.195 us; speedup 1.0000x reference)
//
#include <hip/hip_runtime.h>
#include <hip/hip_bf16.h>
#include <stdint.h>

// SSMBlock: x -> silu(x Wg^T) -> s = xg Wsp^T -> scan(decay) -> out = states WcT^T + xg W2^T + b_out
// R10 = R9 GEMM (2-phase, both-sides-XOR coalesced staging) + scan fusion:
//   - chunk-carry computation fused into G2's LDS epilogue (removes scan_partial pass)
//   - carry exclusive-prefix fused into scan_final (removes scan_carry dispatch)

typedef __bf16 bf16_t;
typedef bf16_t bf16x8 __attribute__((ext_vector_type(8)));
typedef bf16_t bf16x4 __attribute__((ext_vector_type(4)));
typedef float  f32x4  __attribute__((ext_vector_type(4)));

static __device__ __forceinline__ void async_copy16(bf16_t* lds, const bf16_t* g) {
    __builtin_amdgcn_global_load_lds((const __attribute__((address_space(1))) void*)g,
                                     (__attribute__((address_space(3))) void*)lds, 16, 0, 0);
}

// Block 256 thr / 4 waves (2x2); tile 128x128, BK=64, wave tile 64x64, acc 4x4 f32x4.
// LDS per buf: [row(128)][k(64)] bf16, 16 KB; phys chunk16 = k_chunk ^ (row&7).
// Stage: 1KB windows, 8 full cachelines per gll (verified R9: -37us).
// Loop: stage(t+1) FIRST; ds_read(t); MFMA(t); one __syncthreads per tile.
// MODE: 0 = f32 out (+bias), 1 = bf16 out (+bias), 2 = silu -> bf16 (+bias)
// SCAN: fold 64-row chunk carries from the eps tile (G2 only; MODE must be 1).
template <int MODE, int NT, bool SCAN>
__global__ __launch_bounds__(256, 2) void gemm_2ph(
    const bf16_t* __restrict__ A0, const bf16_t* __restrict__ W0,
    const bf16_t* __restrict__ A1, const bf16_t* __restrict__ W1,
    const float* __restrict__ bias, void* __restrict__ outp,
    const float* __restrict__ decay_g, float* __restrict__ carry_g)
{
    constexpr int K = 512;
    __shared__ bf16_t As[2][128 * 64];   // 2 x 16 KB
    __shared__ bf16_t Bs[2][128 * 64];   // 2 x 16 KB
    const int tid = threadIdx.x;
    int bid = blockIdx.x;
    {   // XCD-chunked swizzle (grids are %8==0)
        int nwg = gridDim.x;
        if ((nwg & 7) == 0) bid = (bid & 7) * (nwg >> 3) + (bid >> 3);
    }
    const int m0 = (bid >> 2) << 7, n0 = (bid & 3) << 7;   // tN = 512/128 = 4
    const int l = tid & 63, w = tid >> 6;
    const int wr = w >> 1, wc = w & 1;
    const int lr = l & 15, kc = l >> 4;
    const int rloc = l >> 3, sc = (l & 7) ^ rloc;          // staging source permutation

    float bv[4];
    #pragma unroll
    for (int j = 0; j < 4; ++j)
        bv[j] = bias ? bias[n0 + wc * 64 + j * 16 + lr] : 0.f;

    f32x4 acc[4][4];
    const f32x4 z = {0.f, 0.f, 0.f, 0.f};
    #pragma unroll
    for (int i = 0; i < 4; ++i)
        #pragma unroll
        for (int j = 0; j < 4; ++j) acc[i][j] = z;

    auto stage = [&](int t) {
        const bf16_t* __restrict__ Asrc = (t < 8) ? A0 : A1;
        const bf16_t* __restrict__ Wsrc = (t < 8) ? W0 : W1;
        const int kk = (t & 7) << 6;
        bf16_t* bufA = As[t & 1];
        bf16_t* bufB = Bs[t & 1];
        #pragma unroll
        for (int v = 0; v < 4; ++v) {
            const int win = w * 4 + v;          // rows win*8 .. win*8+7 (1KB window)
            async_copy16(bufA + win * 512,      // wave-uniform base; HW adds lane*16
                         Asrc + (size_t)(m0 + win * 8 + rloc) * K + kk + sc * 8);
            async_copy16(bufB + win * 512,
                         Wsrc + (size_t)(n0 + win * 8 + rloc) * K + kk + sc * 8);
        }
    };

    stage(0);
    __syncthreads();                        // buf0 ready (drains vmcnt)

    #pragma unroll
    for (int t = 0; t < NT; ++t) {
        if (t + 1 < NT) stage(t + 1);       // prefetch next tile FIRST
        const bf16_t* __restrict__ bufA = As[t & 1];
        const bf16_t* __restrict__ bufB = Bs[t & 1];
        bf16x8 a[2][4], b[2][4];            // [ks][frag]
        #pragma unroll
        for (int ks = 0; ks < 2; ++ks) {
            #pragma unroll
            for (int i = 0; i < 4; ++i)
                a[ks][i] = *(const bf16x8*)(bufA + (wr * 64 + i * 16 + lr) * 64
                                            + (((ks * 4 + kc) ^ (lr & 7)) << 3));
            #pragma unroll
            for (int j = 0; j < 4; ++j)
                b[ks][j] = *(const bf16x8*)(bufB + (wc * 64 + j * 16 + lr) * 64
                                            + (((ks * 4 + kc) ^ (lr & 7)) << 3));
        }
        #pragma unroll
        for (int ks = 0; ks < 2; ++ks)
            #pragma unroll
            for (int i = 0; i < 4; ++i)
                #pragma unroll
                for (int j = 0; j < 4; ++j)
                    acc[i][j] = __builtin_amdgcn_mfma_f32_16x16x32_bf16(
                        a[ks][i], b[ks][j], acc[i][j], 0, 0, 0);
        if (t + 1 < NT) __syncthreads();    // next buf staged + this buf's reads done
    }

    // C/D layout: col = lane&15, row = (lane>>4)*4 + reg
    if (MODE == 0) {
        float* outF = (float*)outp;
        #pragma unroll
        for (int i = 0; i < 4; ++i) {
            const int row = m0 + wr * 64 + i * 16 + kc * 4;
            #pragma unroll
            for (int j = 0; j < 4; ++j) {
                const int col = n0 + wc * 64 + j * 16 + lr;
                #pragma unroll
                for (int r = 0; r < 4; ++r)
                    outF[(size_t)(row + r) * 512 + col] = acc[i][j][r] + bv[j];
            }
        }
    } else {
        // bf16: repack via LDS (reuse As = 32 KB), then 16B/lane coalesced stores
        __syncthreads();                    // all waves done with K-loop LDS
        bf16_t* eps = &As[0][0];            // 128 x 128 bf16 = 32 KB
        #pragma unroll
        for (int i = 0; i < 4; ++i) {
            const int row = wr * 64 + i * 16 + kc * 4;
            #pragma unroll
            for (int j = 0; j < 4; ++j) {
                const int col = wc * 64 + j * 16 + lr;
                #pragma unroll
                for (int r = 0; r < 4; ++r) {
                    float v = acc[i][j][r] + bv[j];
                    if (MODE == 2) v = v / (1.f + __expf(-v));
                    eps[(row + r) * 128 + col] = (bf16_t)v;
                }
            }
        }
        __syncthreads();
        bf16_t* outB = (bf16_t*)outp;
        #pragma unroll
        for (int s2 = 0; s2 < 8; ++s2) {
            const int row = s2 * 16 + (tid >> 4);
            const int col = (tid & 15) * 8;
            *(bf16x8*)(outB + (size_t)(m0 + row) * 512 + n0 + col) =
                *(const bf16x8*)(eps + row * 128 + col);
        }
        if (SCAN) {
            // fused scan_partial: tile = exactly 2 seq-chunks of 64 rows x 128 cols.
            // 256 threads <-> (chunk-half, col). LDS reads: fixed col per lane ->
            // banks col/2 -> 2 lanes/bank (free). Same bf16-rounded values as before.
            const int chalf = tid >> 7, col = tid & 127;
            const int n = n0 + col;
            const float dec = decay_g[n];
            float st = 0.f;
            #pragma unroll 8
            for (int i = 0; i < 64; ++i)
                st = st * dec + (float)eps[(chalf * 64 + i) * 128 + col];
            carry_g[(size_t)((m0 >> 6) + chalf) * 512 + n] = st;   // m0>>6 = b*64 + t/64
        }
    }
}

// fused prep: x->bf16 (all 8192 blocks), weight prep (blocks<1024), decay (blocks<128)
__global__ void prep_all(const float4* __restrict__ x, bf16x4* __restrict__ xb,
                         const float* __restrict__ Wg, const float* __restrict__ Wsp,
                         const float* __restrict__ Wo, const float* __restrict__ Dp,
                         bf16_t* __restrict__ Wg_bf, bf16_t* __restrict__ Wsp_bf,
                         bf16_t* __restrict__ Wo_bf, bf16_t* __restrict__ W2_bf,
                         const float* __restrict__ A_log, float* __restrict__ decay)
{
    const int blk = blockIdx.x, tid = threadIdx.x;
    {   // x -> bf16, 4 floats/thread
        int i = blk * 256 + tid;
        float4 v = x[i];
        bf16x4 o;
        o[0] = (bf16_t)v.x; o[1] = (bf16_t)v.y; o[2] = (bf16_t)v.z; o[3] = (bf16_t)v.w;
        xb[i] = o;
    }
    if (blk < 1024) {
        int i = blk * 256 + tid;          // 512*512 elements
        Wg_bf[i]  = (bf16_t)Wg[i];
        Wsp_bf[i] = (bf16_t)Wsp[i];
        float wo  = Wo[i];
        Wo_bf[i]  = (bf16_t)wo;
        W2_bf[i]  = (bf16_t)(wo * Dp[i & 511]);   // W2[d',d] = W_out[d',d]*D[d]
    }
    if (blk < 128) {
        int d = blk * 4 + (tid >> 6);     // one wave per row of A_log
        int ll = tid & 63;
        const float* row = A_log + (size_t)d * 512;
        float s = 0.f;
        for (int k = ll; k < 512; k += 64) s += expf(row[k]);
        #pragma unroll
        for (int off = 32; off > 0; off >>= 1) s += __shfl_down(s, off);
        if (ll == 0) decay[d] = expf(-s * (1.f / 512.f));  // exp(mean(-exp(A_log)))
    }
}

// fused scan: per (b,ch,n) thread -- exclusive prefix over 64 L2-resident chunk
// carries (ch is block-uniform -> no divergence), then scan own chunk; ch==63
// thread emits state_f. Replaces scan_carry + scan_final.
__global__ void scan_final2(const bf16_t* __restrict__ s, const float* __restrict__ decay,
                            const float* __restrict__ carry, const float* __restrict__ state0,
                            bf16_t* __restrict__ states, float* __restrict__ state_f)
{
    int g = blockIdx.x * 256 + threadIdx.x;       // B*N*64 = 131072
    int n = g & 511, ch = (g >> 9) & 63, b = g >> 15;
    float dec = decay[n];
    float d64 = dec;
    #pragma unroll
    for (int t = 0; t < 6; ++t) d64 *= d64;       // dec^64 via squaring
    float st = state0[b * 512 + n];
    const float* crow = carry + (size_t)b * 64 * 512 + n;
    for (int c = 0; c < ch; ++c)                   // uniform trip count per block
        st = st * d64 + crow[(size_t)c * 512];     // coalesced per-iteration
    size_t base = (size_t)(b * 4096 + ch * 64) * 512 + n;
    #pragma unroll 8
    for (int i = 0; i < 64; ++i) {
        st = st * dec + (float)s[base + (size_t)i * 512];
        states[base + (size_t)i * 512] = (bf16_t)st;
    }
    if (ch == 63) state_f[b * 512 + n] = st;
}

extern "C" void kernel_launch(void* const* d_in, const int* in_sizes, int n_in,
                              void* d_out, int out_size, void* d_ws, size_t ws_size,
                              hipStream_t stream)
{
    const float* x      = (const float*)d_in[0];
    const float* state0 = (const float*)d_in[1];
    const float* W_gate = (const float*)d_in[2];
    const float* b_gate = (const float*)d_in[3];
    const float* W_sp   = (const float*)d_in[4];
    const float* b_sp   = (const float*)d_in[5];
    const float* W_out  = (const float*)d_in[6];
    const float* b_out  = (const float*)d_in[7];
    const float* A_log  = (const float*)d_in[8];
    const float* D_par  = (const float*)d_in[9];
    float* out = (float*)d_out;

    // workspace layout (~51.5 MB)
    char* ws = (char*)d_ws;
    bf16_t* x_bf   = (bf16_t*)ws;                     // 16 MB, reused for states
    bf16_t* states = x_bf;
    bf16_t* xg_bf  = (bf16_t*)(ws + (16u << 20));     // 16 MB
    bf16_t* s_bf   = (bf16_t*)(ws + (32u << 20));     // 16 MB
    bf16_t* Wg_bf  = (bf16_t*)(ws + (48u << 20));     // 5 x 512 KB weights
    bf16_t* Wsp_bf = Wg_bf + 262144;
    bf16_t* Wo_bf  = Wg_bf + 2 * 262144;
    bf16_t* W2_bf  = Wg_bf + 3 * 262144;
    bf16_t* WcT_bf = Wg_bf + 4 * 262144;
    float*  carry  = (float*)(Wg_bf + 5 * 262144);    // 512 KB
    float*  decay  = carry + 131072;                  // 2 KB

    prep_all<<<dim3(8192), dim3(256), 0, stream>>>(
        (const float4*)x, (bf16x4*)x_bf, W_gate, W_sp, W_out, D_par,
        Wg_bf, Wsp_bf, Wo_bf, W2_bf, A_log, decay);

    // WcT[d',n] = sum_d W_out[d',d] * W_sp[n,d]   (M=512 -> grid 4x4 = 16)
    gemm_2ph<1, 8, false><<<dim3(16), dim3(256), 0, stream>>>(
        Wo_bf, Wsp_bf, (const bf16_t*)nullptr, (const bf16_t*)nullptr,
        (const float*)nullptr, (void*)WcT_bf, (const float*)nullptr, (float*)nullptr);
    // xg = silu(x W_gate^T + b_gate)   (grid 128x4 = 512 -> 2 blocks/CU)
    gemm_2ph<2, 8, false><<<dim3(512), dim3(256), 0, stream>>>(
        x_bf, Wg_bf, (const bf16_t*)nullptr, (const bf16_t*)nullptr,
        b_gate, (void*)xg_bf, (const float*)nullptr, (float*)nullptr);
    // s = xg W_sp^T + b_sp, with fused per-chunk carry computation
    gemm_2ph<1, 8, true><<<dim3(512), dim3(256), 0, stream>>>(
        xg_bf, Wsp_bf, (const bf16_t*)nullptr, (const bf16_t*)nullptr,
        b_sp, (void*)s_bf, decay, carry);

    // fused carry-prefix + per-chunk scan + state_f
    scan_final2<<<dim3(512), dim3(256), 0, stream>>>(
        s_bf, decay, carry, state0, states, out + 8388608);

    // out = states WcT^T + xg W2^T + b_out   (concat-K, NT=16)
    gemm_2ph<0, 16, false><<<dim3(512), dim3(256), 0, stream>>>(
        states, WcT_bf, xg_bf, W2_bf, b_out, (void*)out,
        (const float*)nullptr, (float*)nullptr);
}

// Round 12
// 95.179 us; speedup vs baseline: 1.0947x; 1.0947x over previous
//
#include <hip/hip_runtime.h>
#include <hip/hip_bf16.h>
#include <stdint.h>

// SSMBlock: x -> silu(x Wg^T) -> s = xg Wsp^T -> scan(decay) -> out = states WcT^T + xg W2^T + b_out
// R11 = R9 GEMM (2-phase, both-sides-XOR coalesced staging) + G2-fused chunk carries
// (from R10, kept) + R9's tiny scan_carry / scan_final (R10's per-thread prefix redo
// reverted -- it added a 63-deep serial L2 chain per thread).

typedef __bf16 bf16_t;
typedef bf16_t bf16x8 __attribute__((ext_vector_type(8)));
typedef bf16_t bf16x4 __attribute__((ext_vector_type(4)));
typedef float  f32x4  __attribute__((ext_vector_type(4)));

static __device__ __forceinline__ void async_copy16(bf16_t* lds, const bf16_t* g) {
    __builtin_amdgcn_global_load_lds((const __attribute__((address_space(1))) void*)g,
                                     (__attribute__((address_space(3))) void*)lds, 16, 0, 0);
}

// Block 256 thr / 4 waves (2x2); tile 128x128, BK=64, wave tile 64x64, acc 4x4 f32x4.
// LDS per buf: [row(128)][k(64)] bf16, 16 KB; phys chunk16 = k_chunk ^ (row&7).
// Stage: 1KB windows, 8 full cachelines per gll (verified R9: -37us vs gather).
// Loop: stage(t+1) FIRST; ds_read(t); MFMA(t); one __syncthreads per tile.
// MODE: 0 = f32 out (+bias), 1 = bf16 out (+bias), 2 = silu -> bf16 (+bias)
// SCAN: fold 64-row chunk carries from the eps tile (G2 only; MODE must be 1).
template <int MODE, int NT, bool SCAN>
__global__ __launch_bounds__(256, 2) void gemm_2ph(
    const bf16_t* __restrict__ A0, const bf16_t* __restrict__ W0,
    const bf16_t* __restrict__ A1, const bf16_t* __restrict__ W1,
    const float* __restrict__ bias, void* __restrict__ outp,
    const float* __restrict__ decay_g, float* __restrict__ carry_g)
{
    constexpr int K = 512;
    __shared__ bf16_t As[2][128 * 64];   // 2 x 16 KB
    __shared__ bf16_t Bs[2][128 * 64];   // 2 x 16 KB
    const int tid = threadIdx.x;
    int bid = blockIdx.x;
    {   // XCD-chunked swizzle (grids are %8==0)
        int nwg = gridDim.x;
        if ((nwg & 7) == 0) bid = (bid & 7) * (nwg >> 3) + (bid >> 3);
    }
    const int m0 = (bid >> 2) << 7, n0 = (bid & 3) << 7;   // tN = 512/128 = 4
    const int l = tid & 63, w = tid >> 6;
    const int wr = w >> 1, wc = w & 1;
    const int lr = l & 15, kc = l >> 4;
    const int rloc = l >> 3, sc = (l & 7) ^ rloc;          // staging source permutation

    float bv[4];
    #pragma unroll
    for (int j = 0; j < 4; ++j)
        bv[j] = bias ? bias[n0 + wc * 64 + j * 16 + lr] : 0.f;

    f32x4 acc[4][4];
    const f32x4 z = {0.f, 0.f, 0.f, 0.f};
    #pragma unroll
    for (int i = 0; i < 4; ++i)
        #pragma unroll
        for (int j = 0; j < 4; ++j) acc[i][j] = z;

    auto stage = [&](int t) {
        const bf16_t* __restrict__ Asrc = (t < 8) ? A0 : A1;
        const bf16_t* __restrict__ Wsrc = (t < 8) ? W0 : W1;
        const int kk = (t & 7) << 6;
        bf16_t* bufA = As[t & 1];
        bf16_t* bufB = Bs[t & 1];
        #pragma unroll
        for (int v = 0; v < 4; ++v) {
            const int win = w * 4 + v;          // rows win*8 .. win*8+7 (1KB window)
            async_copy16(bufA + win * 512,      // wave-uniform base; HW adds lane*16
                         Asrc + (size_t)(m0 + win * 8 + rloc) * K + kk + sc * 8);
            async_copy16(bufB + win * 512,
                         Wsrc + (size_t)(n0 + win * 8 + rloc) * K + kk + sc * 8);
        }
    };

    stage(0);
    __syncthreads();                        // buf0 ready (drains vmcnt)

    #pragma unroll
    for (int t = 0; t < NT; ++t) {
        if (t + 1 < NT) stage(t + 1);       // prefetch next tile FIRST
        const bf16_t* __restrict__ bufA = As[t & 1];
        const bf16_t* __restrict__ bufB = Bs[t & 1];
        bf16x8 a[2][4], b[2][4];            // [ks][frag]
        #pragma unroll
        for (int ks = 0; ks < 2; ++ks) {
            #pragma unroll
            for (int i = 0; i < 4; ++i)
                a[ks][i] = *(const bf16x8*)(bufA + (wr * 64 + i * 16 + lr) * 64
                                            + (((ks * 4 + kc) ^ (lr & 7)) << 3));
            #pragma unroll
            for (int j = 0; j < 4; ++j)
                b[ks][j] = *(const bf16x8*)(bufB + (wc * 64 + j * 16 + lr) * 64
                                            + (((ks * 4 + kc) ^ (lr & 7)) << 3));
        }
        #pragma unroll
        for (int ks = 0; ks < 2; ++ks)
            #pragma unroll
            for (int i = 0; i < 4; ++i)
                #pragma unroll
                for (int j = 0; j < 4; ++j)
                    acc[i][j] = __builtin_amdgcn_mfma_f32_16x16x32_bf16(
                        a[ks][i], b[ks][j], acc[i][j], 0, 0, 0);
        if (t + 1 < NT) __syncthreads();    // next buf staged + this buf's reads done
    }

    // C/D layout: col = lane&15, row = (lane>>4)*4 + reg
    if (MODE == 0) {
        float* outF = (float*)outp;         // f32: 64B/16-lane group, coalesced
        #pragma unroll
        for (int i = 0; i < 4; ++i) {
            const int row = m0 + wr * 64 + i * 16 + kc * 4;
            #pragma unroll
            for (int j = 0; j < 4; ++j) {
                const int col = n0 + wc * 64 + j * 16 + lr;
                #pragma unroll
                for (int r = 0; r < 4; ++r)
                    outF[(size_t)(row + r) * 512 + col] = acc[i][j][r] + bv[j];
            }
        }
    } else {
        // bf16: repack via LDS (reuse As = 32 KB), then 16B/lane coalesced stores
        __syncthreads();                    // all waves done with K-loop LDS
        bf16_t* eps = &As[0][0];            // 128 x 128 bf16 = 32 KB
        #pragma unroll
        for (int i = 0; i < 4; ++i) {
            const int row = wr * 64 + i * 16 + kc * 4;
            #pragma unroll
            for (int j = 0; j < 4; ++j) {
                const int col = wc * 64 + j * 16 + lr;
                #pragma unroll
                for (int r = 0; r < 4; ++r) {
                    float v = acc[i][j][r] + bv[j];
                    if (MODE == 2) v = v / (1.f + __expf(-v));
                    eps[(row + r) * 128 + col] = (bf16_t)v;
                }
            }
        }
        __syncthreads();
        bf16_t* outB = (bf16_t*)outp;
        #pragma unroll
        for (int s2 = 0; s2 < 8; ++s2) {
            const int row = s2 * 16 + (tid >> 4);
            const int col = (tid & 15) * 8;
            *(bf16x8*)(outB + (size_t)(m0 + row) * 512 + n0 + col) =
                *(const bf16x8*)(eps + row * 128 + col);
        }
        if (SCAN) {
            // fused scan_partial: tile = exactly 2 seq-chunks of 64 rows x 128 cols.
            // 256 threads <-> (chunk-half, col). Fixed col per lane -> 2 lanes/bank
            // (free). Same bf16-rounded values as the old global pass -> bit-identical.
            const int chalf = tid >> 7, col = tid & 127;
            const int n = n0 + col;
            const float dec = decay_g[n];
            float st = 0.f;
            #pragma unroll 8
            for (int i = 0; i < 64; ++i)
                st = st * dec + (float)eps[(chalf * 64 + i) * 128 + col];
            carry_g[(size_t)((m0 >> 6) + chalf) * 512 + n] = st;   // chunk = row/64
        }
    }
}

// fused prep: x->bf16 (all 8192 blocks), weight prep (blocks<1024), decay (blocks<128)
__global__ void prep_all(const float4* __restrict__ x, bf16x4* __restrict__ xb,
                         const float* __restrict__ Wg, const float* __restrict__ Wsp,
                         const float* __restrict__ Wo, const float* __restrict__ Dp,
                         bf16_t* __restrict__ Wg_bf, bf16_t* __restrict__ Wsp_bf,
                         bf16_t* __restrict__ Wo_bf, bf16_t* __restrict__ W2_bf,
                         const float* __restrict__ A_log, float* __restrict__ decay)
{
    const int blk = blockIdx.x, tid = threadIdx.x;
    {   // x -> bf16, 4 floats/thread
        int i = blk * 256 + tid;
        float4 v = x[i];
        bf16x4 o;
        o[0] = (bf16_t)v.x; o[1] = (bf16_t)v.y; o[2] = (bf16_t)v.z; o[3] = (bf16_t)v.w;
        xb[i] = o;
    }
    if (blk < 1024) {
        int i = blk * 256 + tid;          // 512*512 elements
        Wg_bf[i]  = (bf16_t)Wg[i];
        Wsp_bf[i] = (bf16_t)Wsp[i];
        float wo  = Wo[i];
        Wo_bf[i]  = (bf16_t)wo;
        W2_bf[i]  = (bf16_t)(wo * Dp[i & 511]);   // W2[d',d] = W_out[d',d]*D[d]
    }
    if (blk < 128) {
        int d = blk * 4 + (tid >> 6);     // one wave per row of A_log
        int ll = tid & 63;
        const float* row = A_log + (size_t)d * 512;
        float s = 0.f;
        for (int k = ll; k < 512; k += 64) s += expf(row[k]);
        #pragma unroll
        for (int off = 32; off > 0; off >>= 1) s += __shfl_down(s, off);
        if (ll == 0) decay[d] = expf(-s * (1.f / 512.f));  // exp(mean(-exp(A_log)))
    }
}

// tiny cross-chunk prefix: 2048 threads, fixed trip 64 (compiler pipelines loads)
__global__ void scan_carry(const float* __restrict__ carry, const float* __restrict__ decay,
                           const float* __restrict__ state0,
                           float* __restrict__ exc, float* __restrict__ state_f)
{
    int g = blockIdx.x * 256 + threadIdx.x;       // B*N = 2048
    int n = g & 511, b = g >> 9;
    float dec = decay[n];
    float d64 = dec;
    #pragma unroll
    for (int t = 0; t < 6; ++t) d64 *= d64;       // dec^64 via squaring
    float st = state0[g];
    for (int ch = 0; ch < 64; ++ch) {
        size_t idx = (size_t)(b * 64 + ch) * 512 + n;
        exc[idx] = st;                             // exclusive carry-in per chunk
        st = st * d64 + carry[idx];
    }
    state_f[g] = st;                               // final state -> d_out tail
}

__global__ void scan_final(const bf16_t* __restrict__ s, const float* __restrict__ decay,
                           const float* __restrict__ exc, bf16_t* __restrict__ states)
{
    int g = blockIdx.x * 256 + threadIdx.x;       // B*N*64
    int n = g & 511, ch = (g >> 9) & 63, b = g >> 15;
    float dec = decay[n];
    float st = exc[(size_t)(b * 64 + ch) * 512 + n];
    size_t base = (size_t)(b * 4096 + ch * 64) * 512 + n;
    #pragma unroll 8
    for (int i = 0; i < 64; ++i) {
        st = st * dec + (float)s[base + (size_t)i * 512];
        states[base + (size_t)i * 512] = (bf16_t)st;
    }
}

extern "C" void kernel_launch(void* const* d_in, const int* in_sizes, int n_in,
                              void* d_out, int out_size, void* d_ws, size_t ws_size,
                              hipStream_t stream)
{
    const float* x      = (const float*)d_in[0];
    const float* state0 = (const float*)d_in[1];
    const float* W_gate = (const float*)d_in[2];
    const float* b_gate = (const float*)d_in[3];
    const float* W_sp   = (const float*)d_in[4];
    const float* b_sp   = (const float*)d_in[5];
    const float* W_out  = (const float*)d_in[6];
    const float* b_out  = (const float*)d_in[7];
    const float* A_log  = (const float*)d_in[8];
    const float* D_par  = (const float*)d_in[9];
    float* out = (float*)d_out;

    // workspace layout (~51.5 MB)
    char* ws = (char*)d_ws;
    bf16_t* x_bf   = (bf16_t*)ws;                     // 16 MB, reused for states
    bf16_t* states = x_bf;
    bf16_t* xg_bf  = (bf16_t*)(ws + (16u << 20));     // 16 MB
    bf16_t* s_bf   = (bf16_t*)(ws + (32u << 20));     // 16 MB
    bf16_t* Wg_bf  = (bf16_t*)(ws + (48u << 20));     // 5 x 512 KB weights
    bf16_t* Wsp_bf = Wg_bf + 262144;
    bf16_t* Wo_bf  = Wg_bf + 2 * 262144;
    bf16_t* W2_bf  = Wg_bf + 3 * 262144;
    bf16_t* WcT_bf = Wg_bf + 4 * 262144;
    float*  carry  = (float*)(Wg_bf + 5 * 262144);    // 512 KB
    float*  exc    = carry + 131072;                  // 512 KB
    float*  decay  = exc + 131072;                    // 2 KB

    prep_all<<<dim3(8192), dim3(256), 0, stream>>>(
        (const float4*)x, (bf16x4*)x_bf, W_gate, W_sp, W_out, D_par,
        Wg_bf, Wsp_bf, Wo_bf, W2_bf, A_log, decay);

    // WcT[d',n] = sum_d W_out[d',d] * W_sp[n,d]   (M=512 -> grid 4x4 = 16)
    gemm_2ph<1, 8, false><<<dim3(16), dim3(256), 0, stream>>>(
        Wo_bf, Wsp_bf, (const bf16_t*)nullptr, (const bf16_t*)nullptr,
        (const float*)nullptr, (void*)WcT_bf, (const float*)nullptr, (float*)nullptr);
    // xg = silu(x W_gate^T + b_gate)   (grid 128x4 = 512 -> 2 blocks/CU)
    gemm_2ph<2, 8, false><<<dim3(512), dim3(256), 0, stream>>>(
        x_bf, Wg_bf, (const bf16_t*)nullptr, (const bf16_t*)nullptr,
        b_gate, (void*)xg_bf, (const float*)nullptr, (float*)nullptr);
    // s = xg W_sp^T + b_sp, with fused per-chunk carry computation
    gemm_2ph<1, 8, true><<<dim3(512), dim3(256), 0, stream>>>(
        xg_bf, Wsp_bf, (const bf16_t*)nullptr, (const bf16_t*)nullptr,
        b_sp, (void*)s_bf, decay, carry);

    scan_carry<<<dim3(8), dim3(256), 0, stream>>>(carry, decay, state0, exc, out + 8388608);
    scan_final<<<dim3(512), dim3(256), 0, stream>>>(s_bf, decay, exc, states);

    // out = states WcT^T + xg W2^T + b_out   (concat-K, NT=16)
    gemm_2ph<0, 16, false><<<dim3(512), dim3(256), 0, stream>>>(
        states, WcT_bf, xg_bf, W2_bf, b_out, (void*)out,
        (const float*)nullptr, (float*)nullptr);
}

// Round 13
// 85.136 us; speedup vs baseline: 1.2239x; 1.1180x over previous
//
#include <hip/hip_runtime.h>
#include <hip/hip_bf16.h>
#include <stdint.h>

// SSMBlock: x -> silu(x Wg^T) -> s = xg Wsp^T -> scan(decay) -> out = states WcT^T + xg W2^T + b_out
// R12 = R11 + T4 counted-vmcnt K-loop: in-loop __syncthreads (vmcnt(0) drain) replaced
// by s_waitcnt vmcnt(8) + raw s_barrier -- next tile's 8 global_load_lds stay in
// flight across the MFMA phase (m218 lever). Single structural change vs R11.

typedef __bf16 bf16_t;
typedef bf16_t bf16x8 __attribute__((ext_vector_type(8)));
typedef bf16_t bf16x4 __attribute__((ext_vector_type(4)));
typedef float  f32x4  __attribute__((ext_vector_type(4)));

static __device__ __forceinline__ void async_copy16(bf16_t* lds, const bf16_t* g) {
    __builtin_amdgcn_global_load_lds((const __attribute__((address_space(1))) void*)g,
                                     (__attribute__((address_space(3))) void*)lds, 16, 0, 0);
}

// Block 256 thr / 4 waves (2x2); tile 128x128, BK=64, wave tile 64x64, acc 4x4 f32x4.
// LDS per buf: [row(128)][k(64)] bf16, 16 KB; phys chunk16 = k_chunk ^ (row&7).
// Stage: 1KB windows, 8 full cachelines per gll (verified R9). 8 gll per wave per stage.
// K-loop sync (T4): stage(t+1); vmcnt(8) [= tile t's loads done, t+1's in flight];
// s_barrier; ds_read+MFMA; s_barrier [WAR: reads done before next overwrite].
// Last iter: vmcnt(0) (static predicate -- no stage issued, must drain own tile).
// Barrier count uniform across waves (NT compile-time, no divergent branches).
// MODE: 0 = f32 out (+bias), 1 = bf16 out (+bias), 2 = silu -> bf16 (+bias)
// SCAN: fold 64-row chunk carries from the eps tile (G2 only; MODE must be 1).
template <int MODE, int NT, bool SCAN>
__global__ __launch_bounds__(256, 2) void gemm_2ph(
    const bf16_t* __restrict__ A0, const bf16_t* __restrict__ W0,
    const bf16_t* __restrict__ A1, const bf16_t* __restrict__ W1,
    const float* __restrict__ bias, void* __restrict__ outp,
    const float* __restrict__ decay_g, float* __restrict__ carry_g)
{
    constexpr int K = 512;
    __shared__ bf16_t As[2][128 * 64];   // 2 x 16 KB
    __shared__ bf16_t Bs[2][128 * 64];   // 2 x 16 KB
    const int tid = threadIdx.x;
    int bid = blockIdx.x;
    {   // XCD-chunked swizzle (grids are %8==0)
        int nwg = gridDim.x;
        if ((nwg & 7) == 0) bid = (bid & 7) * (nwg >> 3) + (bid >> 3);
    }
    const int m0 = (bid >> 2) << 7, n0 = (bid & 3) << 7;   // tN = 512/128 = 4
    const int l = tid & 63, w = tid >> 6;
    const int wr = w >> 1, wc = w & 1;
    const int lr = l & 15, kc = l >> 4;
    const int rloc = l >> 3, sc = (l & 7) ^ rloc;          // staging source permutation

    float bv[4];
    #pragma unroll
    for (int j = 0; j < 4; ++j)
        bv[j] = bias ? bias[n0 + wc * 64 + j * 16 + lr] : 0.f;

    f32x4 acc[4][4];
    const f32x4 z = {0.f, 0.f, 0.f, 0.f};
    #pragma unroll
    for (int i = 0; i < 4; ++i)
        #pragma unroll
        for (int j = 0; j < 4; ++j) acc[i][j] = z;

    auto stage = [&](int t) {
        const bf16_t* __restrict__ Asrc = (t < 8) ? A0 : A1;
        const bf16_t* __restrict__ Wsrc = (t < 8) ? W0 : W1;
        const int kk = (t & 7) << 6;
        bf16_t* bufA = As[t & 1];
        bf16_t* bufB = Bs[t & 1];
        #pragma unroll
        for (int v = 0; v < 4; ++v) {
            const int win = w * 4 + v;          // rows win*8 .. win*8+7 (1KB window)
            async_copy16(bufA + win * 512,      // wave-uniform base; HW adds lane*16
                         Asrc + (size_t)(m0 + win * 8 + rloc) * K + kk + sc * 8);
            async_copy16(bufB + win * 512,
                         Wsrc + (size_t)(n0 + win * 8 + rloc) * K + kk + sc * 8);
        }
    };

    stage(0);                               // 8 gll in flight; drained by t=0's vmcnt(8)

    #pragma unroll
    for (int t = 0; t < NT; ++t) {
        if (t + 1 < NT) {
            stage(t + 1);                   // +8 gll -> 16 outstanding
            asm volatile("s_waitcnt vmcnt(8)" ::: "memory");   // tile t done; t+1 in flight
        } else {
            asm volatile("s_waitcnt vmcnt(0)" ::: "memory");   // last tile: drain own stage
        }
        __builtin_amdgcn_s_barrier();       // all waves' tile-t stages visible
        const bf16_t* __restrict__ bufA = As[t & 1];
        const bf16_t* __restrict__ bufB = Bs[t & 1];
        bf16x8 a[2][4], b[2][4];            // [ks][frag]
        #pragma unroll
        for (int ks = 0; ks < 2; ++ks) {
            #pragma unroll
            for (int i = 0; i < 4; ++i)
                a[ks][i] = *(const bf16x8*)(bufA + (wr * 64 + i * 16 + lr) * 64
                                            + (((ks * 4 + kc) ^ (lr & 7)) << 3));
            #pragma unroll
            for (int j = 0; j < 4; ++j)
                b[ks][j] = *(const bf16x8*)(bufB + (wc * 64 + j * 16 + lr) * 64
                                            + (((ks * 4 + kc) ^ (lr & 7)) << 3));
        }
        #pragma unroll
        for (int ks = 0; ks < 2; ++ks)
            #pragma unroll
            for (int i = 0; i < 4; ++i)
                #pragma unroll
                for (int j = 0; j < 4; ++j)
                    acc[i][j] = __builtin_amdgcn_mfma_f32_16x16x32_bf16(
                        a[ks][i], b[ks][j], acc[i][j], 0, 0, 0);
        if (t + 1 < NT)
            __builtin_amdgcn_s_barrier();   // reads of buf[t&1] done before overwrite
    }

    // C/D layout: col = lane&15, row = (lane>>4)*4 + reg
    if (MODE == 0) {
        float* outF = (float*)outp;         // f32: 64B/16-lane group, coalesced
        #pragma unroll
        for (int i = 0; i < 4; ++i) {
            const int row = m0 + wr * 64 + i * 16 + kc * 4;
            #pragma unroll
            for (int j = 0; j < 4; ++j) {
                const int col = n0 + wc * 64 + j * 16 + lr;
                #pragma unroll
                for (int r = 0; r < 4; ++r)
                    outF[(size_t)(row + r) * 512 + col] = acc[i][j][r] + bv[j];
            }
        }
    } else {
        // bf16: repack via LDS (reuse As = 32 KB), then 16B/lane coalesced stores
        __syncthreads();                    // all waves done with K-loop LDS
        bf16_t* eps = &As[0][0];            // 128 x 128 bf16 = 32 KB
        #pragma unroll
        for (int i = 0; i < 4; ++i) {
            const int row = wr * 64 + i * 16 + kc * 4;
            #pragma unroll
            for (int j = 0; j < 4; ++j) {
                const int col = wc * 64 + j * 16 + lr;
                #pragma unroll
                for (int r = 0; r < 4; ++r) {
                    float v = acc[i][j][r] + bv[j];
                    if (MODE == 2) v = v / (1.f + __expf(-v));
                    eps[(row + r) * 128 + col] = (bf16_t)v;
                }
            }
        }
        __syncthreads();
        bf16_t* outB = (bf16_t*)outp;
        #pragma unroll
        for (int s2 = 0; s2 < 8; ++s2) {
            const int row = s2 * 16 + (tid >> 4);
            const int col = (tid & 15) * 8;
            *(bf16x8*)(outB + (size_t)(m0 + row) * 512 + n0 + col) =
                *(const bf16x8*)(eps + row * 128 + col);
        }
        if (SCAN) {
            // fused scan_partial: tile = exactly 2 seq-chunks of 64 rows x 128 cols.
            // 256 threads <-> (chunk-half, col). Fixed col per lane -> 2 lanes/bank
            // (free). Same bf16-rounded values as the old global pass -> bit-identical.
            const int chalf = tid >> 7, col = tid & 127;
            const int n = n0 + col;
            const float dec = decay_g[n];
            float st = 0.f;
            #pragma unroll 8
            for (int i = 0; i < 64; ++i)
                st = st * dec + (float)eps[(chalf * 64 + i) * 128 + col];
            carry_g[(size_t)((m0 >> 6) + chalf) * 512 + n] = st;   // chunk = row/64
        }
    }
}

// fused prep: x->bf16 (all 8192 blocks), weight prep (blocks<1024), decay (blocks<128)
__global__ void prep_all(const float4* __restrict__ x, bf16x4* __restrict__ xb,
                         const float* __restrict__ Wg, const float* __restrict__ Wsp,
                         const float* __restrict__ Wo, const float* __restrict__ Dp,
                         bf16_t* __restrict__ Wg_bf, bf16_t* __restrict__ Wsp_bf,
                         bf16_t* __restrict__ Wo_bf, bf16_t* __restrict__ W2_bf,
                         const float* __restrict__ A_log, float* __restrict__ decay)
{
    const int blk = blockIdx.x, tid = threadIdx.x;
    {   // x -> bf16, 4 floats/thread
        int i = blk * 256 + tid;
        float4 v = x[i];
        bf16x4 o;
        o[0] = (bf16_t)v.x; o[1] = (bf16_t)v.y; o[2] = (bf16_t)v.z; o[3] = (bf16_t)v.w;
        xb[i] = o;
    }
    if (blk < 1024) {
        int i = blk * 256 + tid;          // 512*512 elements
        Wg_bf[i]  = (bf16_t)Wg[i];
        Wsp_bf[i] = (bf16_t)Wsp[i];
        float wo  = Wo[i];
        Wo_bf[i]  = (bf16_t)wo;
        W2_bf[i]  = (bf16_t)(wo * Dp[i & 511]);   // W2[d',d] = W_out[d',d]*D[d]
    }
    if (blk < 128) {
        int d = blk * 4 + (tid >> 6);     // one wave per row of A_log
        int ll = tid & 63;
        const float* row = A_log + (size_t)d * 512;
        float s = 0.f;
        for (int k = ll; k < 512; k += 64) s += expf(row[k]);
        #pragma unroll
        for (int off = 32; off > 0; off >>= 1) s += __shfl_down(s, off);
        if (ll == 0) decay[d] = expf(-s * (1.f / 512.f));  // exp(mean(-exp(A_log)))
    }
}

// tiny cross-chunk prefix: 2048 threads, fixed trip 64 (compiler pipelines loads)
__global__ void scan_carry(const float* __restrict__ carry, const float* __restrict__ decay,
                           const float* __restrict__ state0,
                           float* __restrict__ exc, float* __restrict__ state_f)
{
    int g = blockIdx.x * 256 + threadIdx.x;       // B*N = 2048
    int n = g & 511, b = g >> 9;
    float dec = decay[n];
    float d64 = dec;
    #pragma unroll
    for (int t = 0; t < 6; ++t) d64 *= d64;       // dec^64 via squaring
    float st = state0[g];
    for (int ch = 0; ch < 64; ++ch) {
        size_t idx = (size_t)(b * 64 + ch) * 512 + n;
        exc[idx] = st;                             // exclusive carry-in per chunk
        st = st * d64 + carry[idx];
    }
    state_f[g] = st;                               // final state -> d_out tail
}

__global__ void scan_final(const bf16_t* __restrict__ s, const float* __restrict__ decay,
                           const float* __restrict__ exc, bf16_t* __restrict__ states)
{
    int g = blockIdx.x * 256 + threadIdx.x;       // B*N*64
    int n = g & 511, ch = (g >> 9) & 63, b = g >> 15;
    float dec = decay[n];
    float st = exc[(size_t)(b * 64 + ch) * 512 + n];
    size_t base = (size_t)(b * 4096 + ch * 64) * 512 + n;
    #pragma unroll 8
    for (int i = 0; i < 64; ++i) {
        st = st * dec + (float)s[base + (size_t)i * 512];
        states[base + (size_t)i * 512] = (bf16_t)st;
    }
}

extern "C" void kernel_launch(void* const* d_in, const int* in_sizes, int n_in,
                              void* d_out, int out_size, void* d_ws, size_t ws_size,
                              hipStream_t stream)
{
    const float* x      = (const float*)d_in[0];
    const float* state0 = (const float*)d_in[1];
    const float* W_gate = (const float*)d_in[2];
    const float* b_gate = (const float*)d_in[3];
    const float* W_sp   = (const float*)d_in[4];
    const float* b_sp   = (const float*)d_in[5];
    const float* W_out  = (const float*)d_in[6];
    const float* b_out  = (const float*)d_in[7];
    const float* A_log  = (const float*)d_in[8];
    const float* D_par  = (const float*)d_in[9];
    float* out = (float*)d_out;

    // workspace layout (~51.5 MB)
    char* ws = (char*)d_ws;
    bf16_t* x_bf   = (bf16_t*)ws;                     // 16 MB, reused for states
    bf16_t* states = x_bf;
    bf16_t* xg_bf  = (bf16_t*)(ws + (16u << 20));     // 16 MB
    bf16_t* s_bf   = (bf16_t*)(ws + (32u << 20));     // 16 MB
    bf16_t* Wg_bf  = (bf16_t*)(ws + (48u << 20));     // 5 x 512 KB weights
    bf16_t* Wsp_bf = Wg_bf + 262144;
    bf16_t* Wo_bf  = Wg_bf + 2 * 262144;
    bf16_t* W2_bf  = Wg_bf + 3 * 262144;
    bf16_t* WcT_bf = Wg_bf + 4 * 262144;
    float*  carry  = (float*)(Wg_bf + 5 * 262144);    // 512 KB
    float*  exc    = carry + 131072;                  // 512 KB
    float*  decay  = exc + 131072;                    // 2 KB

    prep_all<<<dim3(8192), dim3(256), 0, stream>>>(
        (const float4*)x, (bf16x4*)x_bf, W_gate, W_sp, W_out, D_par,
        Wg_bf, Wsp_bf, Wo_bf, W2_bf, A_log, decay);

    // WcT[d',n] = sum_d W_out[d',d] * W_sp[n,d]   (M=512 -> grid 4x4 = 16)
    gemm_2ph<1, 8, false><<<dim3(16), dim3(256), 0, stream>>>(
        Wo_bf, Wsp_bf, (const bf16_t*)nullptr, (const bf16_t*)nullptr,
        (const float*)nullptr, (void*)WcT_bf, (const float*)nullptr, (float*)nullptr);
    // xg = silu(x W_gate^T + b_gate)   (grid 128x4 = 512 -> 2 blocks/CU)
    gemm_2ph<2, 8, false><<<dim3(512), dim3(256), 0, stream>>>(
        x_bf, Wg_bf, (const bf16_t*)nullptr, (const bf16_t*)nullptr,
        b_gate, (void*)xg_bf, (const float*)nullptr, (float*)nullptr);
    // s = xg W_sp^T + b_sp, with fused per-chunk carry computation
    gemm_2ph<1, 8, true><<<dim3(512), dim3(256), 0, stream>>>(
        xg_bf, Wsp_bf, (const bf16_t*)nullptr, (const bf16_t*)nullptr,
        b_sp, (void*)s_bf, decay, carry);

    scan_carry<<<dim3(8), dim3(256), 0, stream>>>(carry, decay, state0, exc, out + 8388608);
    scan_final<<<dim3(512), dim3(256), 0, stream>>>(s_bf, decay, exc, states);

    // out = states WcT^T + xg W2^T + b_out   (concat-K, NT=16)
    gemm_2ph<0, 16, false><<<dim3(512), dim3(256), 0, stream>>>(
        states, WcT_bf, xg_bf, W2_bf, b_out, (void*)out,
        (const float*)nullptr, (float*)nullptr);
}

// Round 14
// 83.297 us; speedup vs baseline: 1.2509x; 1.0221x over previous
//
#include <hip/hip_runtime.h>
#include <hip/hip_bf16.h>
#include <stdint.h>

// SSMBlock: x -> silu(x Wg^T) -> s = xg Wsp^T -> scan(decay) -> out = states WcT^T + xg W2^T + b_out
// R13 = R12 + 8-wave blocks (512 thr), wave-tile 64x32: 16 waves/CU (4/SIMD, was 2).
// Same 128x128 tile, BK=64 double-buffer, XOR-coalesced staging, T4 counted vmcnt.

typedef __bf16 bf16_t;
typedef bf16_t bf16x8 __attribute__((ext_vector_type(8)));
typedef bf16_t bf16x4 __attribute__((ext_vector_type(4)));
typedef float  f32x4  __attribute__((ext_vector_type(4)));

static __device__ __forceinline__ void async_copy16(bf16_t* lds, const bf16_t* g) {
    __builtin_amdgcn_global_load_lds((const __attribute__((address_space(1))) void*)g,
                                     (__attribute__((address_space(3))) void*)lds, 16, 0, 0);
}

// Block 512 thr / 8 waves (2x4); tile 128x128, BK=64; wave tile 64x32; acc 4x2 f32x4.
// LDS per buf: [row(128)][k(64)] bf16, 16 KB; phys chunk16 = k_chunk ^ (row&7).
// Stage: 16 x 1KB windows per matrix, wave w owns 2 (win = w*2+v) -> 4 gll/wave/stage.
// K-loop (T4): stage(t+1); vmcnt(4) [tile t done, t+1 in flight]; s_barrier;
// ds_read+MFMA; s_barrier. Last iter vmcnt(0). Uniform barrier counts.
// MODE: 0 = f32 out (+bias), 1 = bf16 out (+bias), 2 = silu -> bf16 (+bias)
// SCAN: fold 64-row chunk carries from eps tile (G2 only; MODE must be 1).
template <int MODE, int NT, bool SCAN>
__global__ __launch_bounds__(512, 4) void gemm_2ph(
    const bf16_t* __restrict__ A0, const bf16_t* __restrict__ W0,
    const bf16_t* __restrict__ A1, const bf16_t* __restrict__ W1,
    const float* __restrict__ bias, void* __restrict__ outp,
    const float* __restrict__ decay_g, float* __restrict__ carry_g)
{
    constexpr int K = 512;
    __shared__ bf16_t As[2][128 * 64];   // 2 x 16 KB
    __shared__ bf16_t Bs[2][128 * 64];   // 2 x 16 KB
    const int tid = threadIdx.x;
    int bid = blockIdx.x;
    {   // XCD-chunked swizzle (grids are %8==0)
        int nwg = gridDim.x;
        if ((nwg & 7) == 0) bid = (bid & 7) * (nwg >> 3) + (bid >> 3);
    }
    const int m0 = (bid >> 2) << 7, n0 = (bid & 3) << 7;   // tN = 512/128 = 4
    const int l = tid & 63, w = tid >> 6;                  // 8 waves
    const int wr = w >> 2, wc = w & 3;                     // 2 x 4 wave grid
    const int lr = l & 15, kc = l >> 4;
    const int rloc = l >> 3, sc = (l & 7) ^ rloc;          // staging source permutation

    float bv[2];
    #pragma unroll
    for (int j = 0; j < 2; ++j)
        bv[j] = bias ? bias[n0 + wc * 32 + j * 16 + lr] : 0.f;

    f32x4 acc[4][2];
    const f32x4 z = {0.f, 0.f, 0.f, 0.f};
    #pragma unroll
    for (int i = 0; i < 4; ++i)
        #pragma unroll
        for (int j = 0; j < 2; ++j) acc[i][j] = z;

    auto stage = [&](int t) {
        const bf16_t* __restrict__ Asrc = (t < 8) ? A0 : A1;
        const bf16_t* __restrict__ Wsrc = (t < 8) ? W0 : W1;
        const int kk = (t & 7) << 6;
        bf16_t* bufA = As[t & 1];
        bf16_t* bufB = Bs[t & 1];
        #pragma unroll
        for (int v = 0; v < 2; ++v) {
            const int win = w * 2 + v;          // rows win*8 .. win*8+7 (1KB window)
            async_copy16(bufA + win * 512,      // wave-uniform base; HW adds lane*16
                         Asrc + (size_t)(m0 + win * 8 + rloc) * K + kk + sc * 8);
            async_copy16(bufB + win * 512,
                         Wsrc + (size_t)(n0 + win * 8 + rloc) * K + kk + sc * 8);
        }
    };

    stage(0);                               // 4 gll in flight

    #pragma unroll
    for (int t = 0; t < NT; ++t) {
        if (t + 1 < NT) {
            stage(t + 1);                   // +4 gll -> 8 outstanding
            asm volatile("s_waitcnt vmcnt(4)" ::: "memory");   // tile t done; t+1 in flight
        } else {
            asm volatile("s_waitcnt vmcnt(0)" ::: "memory");   // last tile: drain own stage
        }
        __builtin_amdgcn_s_barrier();       // all waves' tile-t stages visible
        const bf16_t* __restrict__ bufA = As[t & 1];
        const bf16_t* __restrict__ bufB = Bs[t & 1];
        bf16x8 a[2][4], b[2][2];            // [ks][frag]
        #pragma unroll
        for (int ks = 0; ks < 2; ++ks) {
            #pragma unroll
            for (int i = 0; i < 4; ++i)
                a[ks][i] = *(const bf16x8*)(bufA + (wr * 64 + i * 16 + lr) * 64
                                            + (((ks * 4 + kc) ^ (lr & 7)) << 3));
            #pragma unroll
            for (int j = 0; j < 2; ++j)
                b[ks][j] = *(const bf16x8*)(bufB + (wc * 32 + j * 16 + lr) * 64
                                            + (((ks * 4 + kc) ^ (lr & 7)) << 3));
        }
        #pragma unroll
        for (int ks = 0; ks < 2; ++ks)
            #pragma unroll
            for (int i = 0; i < 4; ++i)
                #pragma unroll
                for (int j = 0; j < 2; ++j)
                    acc[i][j] = __builtin_amdgcn_mfma_f32_16x16x32_bf16(
                        a[ks][i], b[ks][j], acc[i][j], 0, 0, 0);
        if (t + 1 < NT)
            __builtin_amdgcn_s_barrier();   // reads of buf[t&1] done before overwrite
    }

    // C/D layout: col = lane&15, row = (lane>>4)*4 + reg
    if (MODE == 0) {
        float* outF = (float*)outp;         // f32: 64B/16-lane group, coalesced
        #pragma unroll
        for (int i = 0; i < 4; ++i) {
            const int row = m0 + wr * 64 + i * 16 + kc * 4;
            #pragma unroll
            for (int j = 0; j < 2; ++j) {
                const int col = n0 + wc * 32 + j * 16 + lr;
                #pragma unroll
                for (int r = 0; r < 4; ++r)
                    outF[(size_t)(row + r) * 512 + col] = acc[i][j][r] + bv[j];
            }
        }
    } else {
        // bf16: repack via LDS (reuse As = 32 KB), then 16B/lane coalesced stores
        __syncthreads();                    // all waves done with K-loop LDS
        bf16_t* eps = &As[0][0];            // 128 x 128 bf16 = 32 KB
        #pragma unroll
        for (int i = 0; i < 4; ++i) {
            const int row = wr * 64 + i * 16 + kc * 4;
            #pragma unroll
            for (int j = 0; j < 2; ++j) {
                const int col = wc * 32 + j * 16 + lr;
                #pragma unroll
                for (int r = 0; r < 4; ++r) {
                    float v = acc[i][j][r] + bv[j];
                    if (MODE == 2) v = v / (1.f + __expf(-v));
                    eps[(row + r) * 128 + col] = (bf16_t)v;
                }
            }
        }
        __syncthreads();
        bf16_t* outB = (bf16_t*)outp;
        #pragma unroll
        for (int s2 = 0; s2 < 4; ++s2) {    // 512 thr x 8 elems = 32 rows/pass
            const int row = s2 * 32 + (tid >> 4);
            const int col = (tid & 15) * 8;
            *(bf16x8*)(outB + (size_t)(m0 + row) * 512 + n0 + col) =
                *(const bf16x8*)(eps + row * 128 + col);
        }
        if (SCAN) {
            // fused scan_partial: tile = 2 seq-chunks x 128 cols; first 256 threads.
            if (tid < 256) {
                const int chalf = tid >> 7, col = tid & 127;
                const int n = n0 + col;
                const float dec = decay_g[n];
                float st = 0.f;
                #pragma unroll 8
                for (int i = 0; i < 64; ++i)
                    st = st * dec + (float)eps[(chalf * 64 + i) * 128 + col];
                carry_g[(size_t)((m0 >> 6) + chalf) * 512 + n] = st;   // chunk = row/64
            }
        }
    }
}

// fused prep: x->bf16 (all 8192 blocks), weight prep (blocks<1024), decay (blocks<128)
__global__ void prep_all(const float4* __restrict__ x, bf16x4* __restrict__ xb,
                         const float* __restrict__ Wg, const float* __restrict__ Wsp,
                         const float* __restrict__ Wo, const float* __restrict__ Dp,
                         bf16_t* __restrict__ Wg_bf, bf16_t* __restrict__ Wsp_bf,
                         bf16_t* __restrict__ Wo_bf, bf16_t* __restrict__ W2_bf,
                         const float* __restrict__ A_log, float* __restrict__ decay)
{
    const int blk = blockIdx.x, tid = threadIdx.x;
    {   // x -> bf16, 4 floats/thread
        int i = blk * 256 + tid;
        float4 v = x[i];
        bf16x4 o;
        o[0] = (bf16_t)v.x; o[1] = (bf16_t)v.y; o[2] = (bf16_t)v.z; o[3] = (bf16_t)v.w;
        xb[i] = o;
    }
    if (blk < 1024) {
        int i = blk * 256 + tid;          // 512*512 elements
        Wg_bf[i]  = (bf16_t)Wg[i];
        Wsp_bf[i] = (bf16_t)Wsp[i];
        float wo  = Wo[i];
        Wo_bf[i]  = (bf16_t)wo;
        W2_bf[i]  = (bf16_t)(wo * Dp[i & 511]);   // W2[d',d] = W_out[d',d]*D[d]
    }
    if (blk < 128) {
        int d = blk * 4 + (tid >> 6);     // one wave per row of A_log
        int ll = tid & 63;
        const float* row = A_log + (size_t)d * 512;
        float s = 0.f;
        for (int k = ll; k < 512; k += 64) s += expf(row[k]);
        #pragma unroll
        for (int off = 32; off > 0; off >>= 1) s += __shfl_down(s, off);
        if (ll == 0) decay[d] = expf(-s * (1.f / 512.f));  // exp(mean(-exp(A_log)))
    }
}

// tiny cross-chunk prefix: 2048 threads, fixed trip 64 (compiler pipelines loads)
__global__ void scan_carry(const float* __restrict__ carry, const float* __restrict__ decay,
                           const float* __restrict__ state0,
                           float* __restrict__ exc, float* __restrict__ state_f)
{
    int g = blockIdx.x * 256 + threadIdx.x;       // B*N = 2048
    int n = g & 511, b = g >> 9;
    float dec = decay[n];
    float d64 = dec;
    #pragma unroll
    for (int t = 0; t < 6; ++t) d64 *= d64;       // dec^64 via squaring
    float st = state0[g];
    for (int ch = 0; ch < 64; ++ch) {
        size_t idx = (size_t)(b * 64 + ch) * 512 + n;
        exc[idx] = st;                             // exclusive carry-in per chunk
        st = st * d64 + carry[idx];
    }
    state_f[g] = st;                               // final state -> d_out tail
}

__global__ void scan_final(const bf16_t* __restrict__ s, const float* __restrict__ decay,
                           const float* __restrict__ exc, bf16_t* __restrict__ states)
{
    int g = blockIdx.x * 256 + threadIdx.x;       // B*N*64
    int n = g & 511, ch = (g >> 9) & 63, b = g >> 15;
    float dec = decay[n];
    float st = exc[(size_t)(b * 64 + ch) * 512 + n];
    size_t base = (size_t)(b * 4096 + ch * 64) * 512 + n;
    #pragma unroll 8
    for (int i = 0; i < 64; ++i) {
        st = st * dec + (float)s[base + (size_t)i * 512];
        states[base + (size_t)i * 512] = (bf16_t)st;
    }
}

extern "C" void kernel_launch(void* const* d_in, const int* in_sizes, int n_in,
                              void* d_out, int out_size, void* d_ws, size_t ws_size,
                              hipStream_t stream)
{
    const float* x      = (const float*)d_in[0];
    const float* state0 = (const float*)d_in[1];
    const float* W_gate = (const float*)d_in[2];
    const float* b_gate = (const float*)d_in[3];
    const float* W_sp   = (const float*)d_in[4];
    const float* b_sp   = (const float*)d_in[5];
    const float* W_out  = (const float*)d_in[6];
    const float* b_out  = (const float*)d_in[7];
    const float* A_log  = (const float*)d_in[8];
    const float* D_par  = (const float*)d_in[9];
    float* out = (float*)d_out;

    // workspace layout (~51.5 MB)
    char* ws = (char*)d_ws;
    bf16_t* x_bf   = (bf16_t*)ws;                     // 16 MB, reused for states
    bf16_t* states = x_bf;
    bf16_t* xg_bf  = (bf16_t*)(ws + (16u << 20));     // 16 MB
    bf16_t* s_bf   = (bf16_t*)(ws + (32u << 20));     // 16 MB
    bf16_t* Wg_bf  = (bf16_t*)(ws + (48u << 20));     // 5 x 512 KB weights
    bf16_t* Wsp_bf = Wg_bf + 262144;
    bf16_t* Wo_bf  = Wg_bf + 2 * 262144;
    bf16_t* W2_bf  = Wg_bf + 3 * 262144;
    bf16_t* WcT_bf = Wg_bf + 4 * 262144;
    float*  carry  = (float*)(Wg_bf + 5 * 262144);    // 512 KB
    float*  exc    = carry + 131072;                  // 512 KB
    float*  decay  = exc + 131072;                    // 2 KB

    prep_all<<<dim3(8192), dim3(256), 0, stream>>>(
        (const float4*)x, (bf16x4*)x_bf, W_gate, W_sp, W_out, D_par,
        Wg_bf, Wsp_bf, Wo_bf, W2_bf, A_log, decay);

    // WcT[d',n] = sum_d W_out[d',d] * W_sp[n,d]   (M=512 -> grid 4x4 = 16)
    gemm_2ph<1, 8, false><<<dim3(16), dim3(512), 0, stream>>>(
        Wo_bf, Wsp_bf, (const bf16_t*)nullptr, (const bf16_t*)nullptr,
        (const float*)nullptr, (void*)WcT_bf, (const float*)nullptr, (float*)nullptr);
    // xg = silu(x W_gate^T + b_gate)   (grid 128x4 = 512 -> 2 blocks/CU)
    gemm_2ph<2, 8, false><<<dim3(512), dim3(512), 0, stream>>>(
        x_bf, Wg_bf, (const bf16_t*)nullptr, (const bf16_t*)nullptr,
        b_gate, (void*)xg_bf, (const float*)nullptr, (float*)nullptr);
    // s = xg W_sp^T + b_sp, with fused per-chunk carry computation
    gemm_2ph<1, 8, true><<<dim3(512), dim3(512), 0, stream>>>(
        xg_bf, Wsp_bf, (const bf16_t*)nullptr, (const bf16_t*)nullptr,
        b_sp, (void*)s_bf, decay, carry);

    scan_carry<<<dim3(8), dim3(256), 0, stream>>>(carry, decay, state0, exc, out + 8388608);
    scan_final<<<dim3(512), dim3(256), 0, stream>>>(s_bf, decay, exc, states);

    // out = states WcT^T + xg W2^T + b_out   (concat-K, NT=16)
    gemm_2ph<0, 16, false><<<dim3(512), dim3(512), 0, stream>>>(
        states, WcT_bf, xg_bf, W2_bf, b_out, (void*)out,
        (const float*)nullptr, (float*)nullptr);
}

// Round 15
// 83.076 us; speedup vs baseline: 1.2542x; 1.0027x over previous
//
#include <hip/hip_runtime.h>
#include <hip/hip_bf16.h>
#include <stdint.h>

// SSMBlock: x -> silu(x Wg^T) -> s = xg Wsp^T -> scan(decay) -> out = states WcT^T + xg W2^T + b_out
// R14 = R13 + F32A path for G1: A staged f32->bf16 via regs+ds_write (T14 split, one
// K-tile of flight), B via global_load_lds; x-conversion pass deleted from prep_all.

typedef __bf16 bf16_t;
typedef bf16_t bf16x8 __attribute__((ext_vector_type(8)));
typedef bf16_t bf16x4 __attribute__((ext_vector_type(4)));
typedef float  f32x4  __attribute__((ext_vector_type(4)));

static __device__ __forceinline__ void async_copy16(bf16_t* lds, const bf16_t* g) {
    __builtin_amdgcn_global_load_lds((const __attribute__((address_space(1))) void*)g,
                                     (__attribute__((address_space(3))) void*)lds, 16, 0, 0);
}

// Block 512 thr / 8 waves (2x4); tile 128x128, BK=64; wave tile 64x32; acc 4x2 f32x4.
// LDS per buf: [row(128)][k(64)] bf16, 16 KB; phys chunk16 = k_chunk ^ (row&7).
// bf16 path (F32A=0): 16 x 1KB windows/matrix, wave owns 2 each -> 4 gll/stage;
//   K-loop: stage(t+1); vmcnt(4); s_barrier; ds_read+MFMA; s_barrier. Last iter vmcnt(0).
// f32-A path (F32A=1, G1): A = f32 source. Per thread: row=tid>>2, q=tid&3; 4 float4
//   loads (64B contiguous), cast RNE, 2 ds_write_b128 at XOR'd chunks (bank-free).
//   B: 2 gll/wave. 6 vm ops/iter: top wait vmcnt(2) [A(t) done]; write A(t);
//   issue A(t+1) [pinned before] B(t+1); wait vmcnt(6)+lgkmcnt(0); barrier; MFMA; barrier.
// MODE: 0 = f32 out (+bias), 1 = bf16 out (+bias), 2 = silu -> bf16 (+bias)
// SCAN: fold 64-row chunk carries from eps tile (G2 only; MODE must be 1).
template <int MODE, int NT, bool SCAN, bool F32A>
__global__ __launch_bounds__(512, 4) void gemm_2ph(
    const void* __restrict__ A0v, const bf16_t* __restrict__ W0,
    const bf16_t* __restrict__ A1, const bf16_t* __restrict__ W1,
    const float* __restrict__ bias, void* __restrict__ outp,
    const float* __restrict__ decay_g, float* __restrict__ carry_g)
{
    constexpr int K = 512;
    __shared__ bf16_t As[2][128 * 64];   // 2 x 16 KB
    __shared__ bf16_t Bs[2][128 * 64];   // 2 x 16 KB
    const int tid = threadIdx.x;
    int bid = blockIdx.x;
    {   // XCD-chunked swizzle (grids are %8==0)
        int nwg = gridDim.x;
        if ((nwg & 7) == 0) bid = (bid & 7) * (nwg >> 3) + (bid >> 3);
    }
    const int m0 = (bid >> 2) << 7, n0 = (bid & 3) << 7;   // tN = 512/128 = 4
    const int l = tid & 63, w = tid >> 6;                  // 8 waves
    const int wr = w >> 2, wc = w & 3;                     // 2 x 4 wave grid
    const int lr = l & 15, kc = l >> 4;
    const int rloc = l >> 3, sc = (l & 7) ^ rloc;          // gll source permutation

    float bv[2];
    #pragma unroll
    for (int j = 0; j < 2; ++j)
        bv[j] = bias ? bias[n0 + wc * 32 + j * 16 + lr] : 0.f;

    f32x4 acc[4][2];
    const f32x4 z = {0.f, 0.f, 0.f, 0.f};
    #pragma unroll
    for (int i = 0; i < 4; ++i)
        #pragma unroll
        for (int j = 0; j < 2; ++j) acc[i][j] = z;

    const bf16_t* __restrict__ A0b = (const bf16_t*)A0v;   // bf16 path
    const float*  __restrict__ A0f = (const float*)A0v;    // f32 path
    const int arow = tid >> 2, aq = tid & 3;               // F32A mapping

    // bf16 full stage (A+B, 4 gll/wave)
    auto stage = [&](int t) {
        const bf16_t* __restrict__ Asrc = (t < 8) ? A0b : A1;
        const bf16_t* __restrict__ Wsrc = (t < 8) ? W0 : W1;
        const int kk = (t & 7) << 6;
        bf16_t* bufA = As[t & 1];
        bf16_t* bufB = Bs[t & 1];
        #pragma unroll
        for (int v = 0; v < 2; ++v) {
            const int win = w * 2 + v;          // rows win*8 .. +7 (1KB window)
            async_copy16(bufA + win * 512,
                         Asrc + (size_t)(m0 + win * 8 + rloc) * K + kk + sc * 8);
            async_copy16(bufB + win * 512,
                         Wsrc + (size_t)(n0 + win * 8 + rloc) * K + kk + sc * 8);
        }
    };
    // F32A: B-only gll stage (2/wave)
    auto stageB = [&](int t) {
        const int kk = (t & 7) << 6;
        bf16_t* bufB = Bs[t & 1];
        #pragma unroll
        for (int v = 0; v < 2; ++v) {
            const int win = w * 2 + v;
            async_copy16(bufB + win * 512,
                         W0 + (size_t)(n0 + win * 8 + rloc) * K + kk + sc * 8);
        }
    };
    float4 arA[4];
    auto issueA = [&](int t) {              // 4 independent float4 loads (64B)
        const float* p = A0f + (size_t)(m0 + arow) * K + ((t & 7) << 6) + aq * 16;
        arA[0] = ((const float4*)p)[0];
        arA[1] = ((const float4*)p)[1];
        arA[2] = ((const float4*)p)[2];
        arA[3] = ((const float4*)p)[3];
    };
    auto writeA = [&](int t) {              // cast RNE + 2 swizzled ds_write_b128
        bf16x8 v0, v1;
        v0[0]=(bf16_t)arA[0].x; v0[1]=(bf16_t)arA[0].y; v0[2]=(bf16_t)arA[0].z; v0[3]=(bf16_t)arA[0].w;
        v0[4]=(bf16_t)arA[1].x; v0[5]=(bf16_t)arA[1].y; v0[6]=(bf16_t)arA[1].z; v0[7]=(bf16_t)arA[1].w;
        v1[0]=(bf16_t)arA[2].x; v1[1]=(bf16_t)arA[2].y; v1[2]=(bf16_t)arA[2].z; v1[3]=(bf16_t)arA[2].w;
        v1[4]=(bf16_t)arA[3].x; v1[5]=(bf16_t)arA[3].y; v1[6]=(bf16_t)arA[3].z; v1[7]=(bf16_t)arA[3].w;
        bf16_t* bufA = As[t & 1];
        *(bf16x8*)(bufA + arow * 64 + (((aq * 2    ) ^ (arow & 7)) << 3)) = v0;
        *(bf16x8*)(bufA + arow * 64 + (((aq * 2 + 1) ^ (arow & 7)) << 3)) = v1;
    };

    if (F32A) { issueA(0); asm volatile("" ::: "memory"); stageB(0); }
    else      { stage(0); }

    #pragma unroll
    for (int t = 0; t < NT; ++t) {
        if (F32A) {
            asm volatile("s_waitcnt vmcnt(2)" ::: "memory");   // A(t) loaded; B(t) may fly
            writeA(t);
            if (t + 1 < NT) {
                issueA(t + 1);
                asm volatile("" ::: "memory");                 // pin A-issue before B-issue
                stageB(t + 1);                                 // outstanding: 2+4+2 = 8
                asm volatile("s_waitcnt vmcnt(6) lgkmcnt(0)" ::: "memory"); // B(t) done, writes visible
            } else {
                asm volatile("s_waitcnt vmcnt(0) lgkmcnt(0)" ::: "memory");
            }
        } else {
            if (t + 1 < NT) {
                stage(t + 1);                                  // +4 gll -> 8 outstanding
                asm volatile("s_waitcnt vmcnt(4)" ::: "memory");
            } else {
                asm volatile("s_waitcnt vmcnt(0)" ::: "memory");
            }
        }
        __builtin_amdgcn_s_barrier();       // tile t visible to all waves
        const bf16_t* __restrict__ bufA = As[t & 1];
        const bf16_t* __restrict__ bufB = Bs[t & 1];
        bf16x8 a[2][4], b[2][2];            // [ks][frag]
        #pragma unroll
        for (int ks = 0; ks < 2; ++ks) {
            #pragma unroll
            for (int i = 0; i < 4; ++i)
                a[ks][i] = *(const bf16x8*)(bufA + (wr * 64 + i * 16 + lr) * 64
                                            + (((ks * 4 + kc) ^ (lr & 7)) << 3));
            #pragma unroll
            for (int j = 0; j < 2; ++j)
                b[ks][j] = *(const bf16x8*)(bufB + (wc * 32 + j * 16 + lr) * 64
                                            + (((ks * 4 + kc) ^ (lr & 7)) << 3));
        }
        #pragma unroll
        for (int ks = 0; ks < 2; ++ks)
            #pragma unroll
            for (int i = 0; i < 4; ++i)
                #pragma unroll
                for (int j = 0; j < 2; ++j)
                    acc[i][j] = __builtin_amdgcn_mfma_f32_16x16x32_bf16(
                        a[ks][i], b[ks][j], acc[i][j], 0, 0, 0);
        if (t + 1 < NT)
            __builtin_amdgcn_s_barrier();   // reads of buf[t&1] done before overwrite
    }

    // C/D layout: col = lane&15, row = (lane>>4)*4 + reg
    if (MODE == 0) {
        float* outF = (float*)outp;         // f32: 64B/16-lane group, coalesced
        #pragma unroll
        for (int i = 0; i < 4; ++i) {
            const int row = m0 + wr * 64 + i * 16 + kc * 4;
            #pragma unroll
            for (int j = 0; j < 2; ++j) {
                const int col = n0 + wc * 32 + j * 16 + lr;
                #pragma unroll
                for (int r = 0; r < 4; ++r)
                    outF[(size_t)(row + r) * 512 + col] = acc[i][j][r] + bv[j];
            }
        }
    } else {
        // bf16: repack via LDS (reuse As = 32 KB), then 16B/lane coalesced stores
        __syncthreads();                    // all waves done with K-loop LDS
        bf16_t* eps = &As[0][0];            // 128 x 128 bf16 = 32 KB
        #pragma unroll
        for (int i = 0; i < 4; ++i) {
            const int row = wr * 64 + i * 16 + kc * 4;
            #pragma unroll
            for (int j = 0; j < 2; ++j) {
                const int col = wc * 32 + j * 16 + lr;
                #pragma unroll
                for (int r = 0; r < 4; ++r) {
                    float v = acc[i][j][r] + bv[j];
                    if (MODE == 2) v = v / (1.f + __expf(-v));
                    eps[(row + r) * 128 + col] = (bf16_t)v;
                }
            }
        }
        __syncthreads();
        bf16_t* outB = (bf16_t*)outp;
        #pragma unroll
        for (int s2 = 0; s2 < 4; ++s2) {    // 512 thr x 8 elems = 32 rows/pass
            const int row = s2 * 32 + (tid >> 4);
            const int col = (tid & 15) * 8;
            *(bf16x8*)(outB + (size_t)(m0 + row) * 512 + n0 + col) =
                *(const bf16x8*)(eps + row * 128 + col);
        }
        if (SCAN) {
            // fused scan_partial: tile = 2 seq-chunks x 128 cols; first 256 threads.
            if (tid < 256) {
                const int chalf = tid >> 7, col = tid & 127;
                const int n = n0 + col;
                const float dec = decay_g[n];
                float st = 0.f;
                #pragma unroll 8
                for (int i = 0; i < 64; ++i)
                    st = st * dec + (float)eps[(chalf * 64 + i) * 128 + col];
                carry_g[(size_t)((m0 >> 6) + chalf) * 512 + n] = st;   // chunk = row/64
            }
        }
    }
}

// prep: weight conversion (1024 blocks) + decay (first 128 blocks). x stays f32.
__global__ void prep_all(const float* __restrict__ Wg, const float* __restrict__ Wsp,
                         const float* __restrict__ Wo, const float* __restrict__ Dp,
                         bf16_t* __restrict__ Wg_bf, bf16_t* __restrict__ Wsp_bf,
                         bf16_t* __restrict__ Wo_bf, bf16_t* __restrict__ W2_bf,
                         const float* __restrict__ A_log, float* __restrict__ decay)
{
    const int blk = blockIdx.x, tid = threadIdx.x;
    {
        int i = blk * 256 + tid;          // 512*512 elements
        Wg_bf[i]  = (bf16_t)Wg[i];
        Wsp_bf[i] = (bf16_t)Wsp[i];
        float wo  = Wo[i];
        Wo_bf[i]  = (bf16_t)wo;
        W2_bf[i]  = (bf16_t)(wo * Dp[i & 511]);   // W2[d',d] = W_out[d',d]*D[d]
    }
    if (blk < 128) {
        int d = blk * 4 + (tid >> 6);     // one wave per row of A_log
        int ll = tid & 63;
        const float* row = A_log + (size_t)d * 512;
        float s = 0.f;
        for (int k = ll; k < 512; k += 64) s += expf(row[k]);
        #pragma unroll
        for (int off = 32; off > 0; off >>= 1) s += __shfl_down(s, off);
        if (ll == 0) decay[d] = expf(-s * (1.f / 512.f));  // exp(mean(-exp(A_log)))
    }
}

// tiny cross-chunk prefix: 2048 threads, fixed trip 64 (compiler pipelines loads)
__global__ void scan_carry(const float* __restrict__ carry, const float* __restrict__ decay,
                           const float* __restrict__ state0,
                           float* __restrict__ exc, float* __restrict__ state_f)
{
    int g = blockIdx.x * 256 + threadIdx.x;       // B*N = 2048
    int n = g & 511, b = g >> 9;
    float dec = decay[n];
    float d64 = dec;
    #pragma unroll
    for (int t = 0; t < 6; ++t) d64 *= d64;       // dec^64 via squaring
    float st = state0[g];
    for (int ch = 0; ch < 64; ++ch) {
        size_t idx = (size_t)(b * 64 + ch) * 512 + n;
        exc[idx] = st;                             // exclusive carry-in per chunk
        st = st * d64 + carry[idx];
    }
    state_f[g] = st;                               // final state -> d_out tail
}

__global__ void scan_final(const bf16_t* __restrict__ s, const float* __restrict__ decay,
                           const float* __restrict__ exc, bf16_t* __restrict__ states)
{
    int g = blockIdx.x * 256 + threadIdx.x;       // B*N*64
    int n = g & 511, ch = (g >> 9) & 63, b = g >> 15;
    float dec = decay[n];
    float st = exc[(size_t)(b * 64 + ch) * 512 + n];
    size_t base = (size_t)(b * 4096 + ch * 64) * 512 + n;
    #pragma unroll 8
    for (int i = 0; i < 64; ++i) {
        st = st * dec + (float)s[base + (size_t)i * 512];
        states[base + (size_t)i * 512] = (bf16_t)st;
    }
}

extern "C" void kernel_launch(void* const* d_in, const int* in_sizes, int n_in,
                              void* d_out, int out_size, void* d_ws, size_t ws_size,
                              hipStream_t stream)
{
    const float* x      = (const float*)d_in[0];
    const float* state0 = (const float*)d_in[1];
    const float* W_gate = (const float*)d_in[2];
    const float* b_gate = (const float*)d_in[3];
    const float* W_sp   = (const float*)d_in[4];
    const float* b_sp   = (const float*)d_in[5];
    const float* W_out  = (const float*)d_in[6];
    const float* b_out  = (const float*)d_in[7];
    const float* A_log  = (const float*)d_in[8];
    const float* D_par  = (const float*)d_in[9];
    float* out = (float*)d_out;

    // workspace layout (~51.5 MB)
    char* ws = (char*)d_ws;
    bf16_t* states = (bf16_t*)ws;                     // 16 MB
    bf16_t* xg_bf  = (bf16_t*)(ws + (16u << 20));     // 16 MB
    bf16_t* s_bf   = (bf16_t*)(ws + (32u << 20));     // 16 MB
    bf16_t* Wg_bf  = (bf16_t*)(ws + (48u << 20));     // 5 x 512 KB weights
    bf16_t* Wsp_bf = Wg_bf + 262144;
    bf16_t* Wo_bf  = Wg_bf + 2 * 262144;
    bf16_t* W2_bf  = Wg_bf + 3 * 262144;
    bf16_t* WcT_bf = Wg_bf + 4 * 262144;
    float*  carry  = (float*)(Wg_bf + 5 * 262144);    // 512 KB
    float*  exc    = carry + 131072;                  // 512 KB
    float*  decay  = exc + 131072;                    // 2 KB

    prep_all<<<dim3(1024), dim3(256), 0, stream>>>(
        W_gate, W_sp, W_out, D_par, Wg_bf, Wsp_bf, Wo_bf, W2_bf, A_log, decay);

    // WcT[d',n] = sum_d W_out[d',d] * W_sp[n,d]   (M=512 -> grid 4x4 = 16)
    gemm_2ph<1, 8, false, false><<<dim3(16), dim3(512), 0, stream>>>(
        (const void*)Wo_bf, Wsp_bf, (const bf16_t*)nullptr, (const bf16_t*)nullptr,
        (const float*)nullptr, (void*)WcT_bf, (const float*)nullptr, (float*)nullptr);
    // xg = silu(x W_gate^T + b_gate)  -- A read directly as f32 (T14 reg-staged)
    gemm_2ph<2, 8, false, true><<<dim3(512), dim3(512), 0, stream>>>(
        (const void*)x, Wg_bf, (const bf16_t*)nullptr, (const bf16_t*)nullptr,
        b_gate, (void*)xg_bf, (const float*)nullptr, (float*)nullptr);
    // s = xg W_sp^T + b_sp, with fused per-chunk carry computation
    gemm_2ph<1, 8, true, false><<<dim3(512), dim3(512), 0, stream>>>(
        (const void*)xg_bf, Wsp_bf, (const bf16_t*)nullptr, (const bf16_t*)nullptr,
        b_sp, (void*)s_bf, decay, carry);

    scan_carry<<<dim3(8), dim3(256), 0, stream>>>(carry, decay, state0, exc, out + 8388608);
    scan_final<<<dim3(512), dim3(256), 0, stream>>>(s_bf, decay, exc, states);

    // out = states WcT^T + xg W2^T + b_out   (concat-K, NT=16)
    gemm_2ph<0, 16, false, false><<<dim3(512), dim3(512), 0, stream>>>(
        (const void*)states, WcT_bf, xg_bf, W2_bf, b_out, (void*)out,
        (const float*)nullptr, (float*)nullptr);
}